// Round 2
// baseline (2003.339 us; speedup 1.0000x reference)
//
#include <hip/hip_runtime.h>
#include <cstdint>
#include <cstddef>

#define NLAYERS 3
#define NN      512
#define DIN     4
#define MTILE   64            // batch rows per workgroup
#define KAUG    544           // 512 (H/T) + 4 (X) + 1 (bias one) + 27 zero pad
#define LDA     552           // LDS row stride in bf16 elems
#define WELEMS  (NN * KAUG)   // one prepared weight matrix, bf16 elems
#define LDS_BYTES (2 * MTILE * LDA * 2)
#define NTHREADS 1024         // 16 waves -> 4 waves/SIMD (1 WG/CU, LDS-limited)

typedef __attribute__((ext_vector_type(8))) short short8;   // 8 x bf16 (4 VGPRs)
typedef __attribute__((ext_vector_type(4))) float f32x4;    // MFMA accumulator

__device__ __forceinline__ short f2bf(float f) {
    union { float f; uint32_t u; } v; v.f = f;
    uint32_t r = v.u + 0x7fffu + ((v.u >> 16) & 1u);   // RNE
    return (short)(r >> 16);
}
__device__ __forceinline__ float bf2f(short s) {
    union { uint32_t u; float f; } v; v.u = ((uint32_t)(uint16_t)s) << 16;
    return v.f;
}
__device__ __forceinline__ float sig_(float x)  { return 1.0f / (1.0f + __expf(-x)); }
__device__ __forceinline__ float tanh_(float x) { return 1.0f - 2.0f / (1.0f + __expf(2.0f * x)); }
__device__ __forceinline__ float silu_(float x) { return x / (1.0f + __expf(-x)); }

// ---------------- prep: 12 transposed + augmented bf16 weight matrices in ws ------------
// mat m = layer*4 + {0:F,1:U,2:O1,3:O2}; Bt[n][kk]:
//   kk<512 -> U[kk][n]; 512..515 -> W[kk-512][n] (0 for O2); 516 -> bias[n]; else 0.
__global__ void prep_kernel(const float* __restrict__ Wf,  const float* __restrict__ Uf,  const float* __restrict__ bf,
                            const float* __restrict__ Wu,  const float* __restrict__ Uu,  const float* __restrict__ bu,
                            const float* __restrict__ Wo1, const float* __restrict__ Uo1, const float* __restrict__ bo1,
                            const float* __restrict__ Wo2, const float* __restrict__ bo2,
                            short* __restrict__ ws) {
    int idx = blockIdx.x * 256 + threadIdx.x;
    int m   = idx / WELEMS;
    if (m >= 12) return;
    int rem = idx - m * WELEMS;
    int n   = rem / KAUG;
    int kk  = rem - n * KAUG;
    int layer = m >> 2, t = m & 3;
    const float* U; const float* W; const float* b;
    switch (t) {
        case 0:  U = Uf;  W = Wf;      b = bf;  break;
        case 1:  U = Uu;  W = Wu;      b = bu;  break;
        case 2:  U = Uo1; W = Wo1;     b = bo1; break;
        default: U = Wo2; W = nullptr; b = bo2; break;
    }
    float val = 0.0f;
    if (kk < NN)             val = U[layer * NN * NN + kk * NN + n];
    else if (kk < NN + DIN)  val = W ? W[layer * DIN * NN + (kk - NN) * NN + n] : 0.0f;
    else if (kk == NN + DIN) val = b[layer * NN + n];
    ws[idx] = f2bf(val);
}

// 32x64 @ K=544 MFMA block: A from LDS (caller pre-offsets to the wave's 32-row group),
// Bt from global. Register double-buffered, unroll-1 loop; base pointers bumped by
// 64 elems/iter so all loads use immediate offsets. Each A fragment feeds 4 MFMAs
// (halved per-MFMA LDS traffic vs the 64x32 shape) while 16 waves keep 4 waves/SIMD.
__device__ __forceinline__ void mm2(const short* __restrict__ Asrc, const short* __restrict__ Bt,
                                    int n0, int l16, int quad, f32x4 (&acc)[2][4]) {
#pragma unroll
    for (int mt = 0; mt < 2; ++mt)
#pragma unroll
        for (int nt = 0; nt < 4; ++nt) acc[mt][nt] = f32x4{0.f, 0.f, 0.f, 0.f};
    const short* aP = Asrc + l16 * LDA + quad * 8;
    const short* bP = Bt + (size_t)(n0 + l16) * KAUG + quad * 8;

    short8 aA[2], bA[4], aB[2], bB[4];
#pragma unroll
    for (int mt = 0; mt < 2; ++mt) aA[mt] = *(const short8*)(aP + mt * 16 * LDA);
#pragma unroll
    for (int nt = 0; nt < 4; ++nt) bA[nt] = *(const short8*)(bP + nt * 16 * KAUG);

#pragma unroll 1
    for (int i = 0; i < 8; ++i) {
#pragma unroll
        for (int mt = 0; mt < 2; ++mt) aB[mt] = *(const short8*)(aP + mt * 16 * LDA + 32);
#pragma unroll
        for (int nt = 0; nt < 4; ++nt) bB[nt] = *(const short8*)(bP + nt * 16 * KAUG + 32);
#pragma unroll
        for (int mt = 0; mt < 2; ++mt)
#pragma unroll
            for (int nt = 0; nt < 4; ++nt)
                acc[mt][nt] = __builtin_amdgcn_mfma_f32_16x16x32_bf16(aA[mt], bA[nt], acc[mt][nt], 0, 0, 0);
#pragma unroll
        for (int mt = 0; mt < 2; ++mt) aA[mt] = *(const short8*)(aP + mt * 16 * LDA + 64);
#pragma unroll
        for (int nt = 0; nt < 4; ++nt) bA[nt] = *(const short8*)(bP + nt * 16 * KAUG + 64);
#pragma unroll
        for (int mt = 0; mt < 2; ++mt)
#pragma unroll
            for (int nt = 0; nt < 4; ++nt)
                acc[mt][nt] = __builtin_amdgcn_mfma_f32_16x16x32_bf16(aB[mt], bB[nt], acc[mt][nt], 0, 0, 0);
        aP += 64; bP += 64;
    }
#pragma unroll
    for (int mt = 0; mt < 2; ++mt)
#pragma unroll
        for (int nt = 0; nt < 4; ++nt)
            acc[mt][nt] = __builtin_amdgcn_mfma_f32_16x16x32_bf16(aA[mt], bA[nt], acc[mt][nt], 0, 0, 0);
}

// ---------------- fused DGM kernel: one 16-wave workgroup = 64 batch rows ----------------
// Wave (wv) -> output tile: rows (wv>>3)*32 .. +32, cols (wv&7)*64 .. +64.
__global__ void __launch_bounds__(NTHREADS, 4)
dgm_kernel(const float* __restrict__ X, const float* __restrict__ W_in, const float* __restrict__ b_in,
           const float* __restrict__ W_out, const float* __restrict__ b_out,
           const short* __restrict__ wmats, float* __restrict__ out) {
    extern __shared__ short lds[];
    short* Hb = lds;                 // [MTILE][LDA]  bf16, cols 512..516 = [X|1]
    short* Tb = lds + MTILE * LDA;   // [MTILE][LDA]  bf16, same augmentation (0,0,0,0,1)

    const int tid  = threadIdx.x;
    const int lane = tid & 63;
    const int wv   = tid >> 6;       // wave 0..15
    const int l16  = lane & 15;
    const int quad = lane >> 4;
    const int n0   = (wv & 7) * 64;  // this wave's 64-column block
    const int r0w  = (wv >> 3) * 32; // this wave's 32-row group
    const int rbase = blockIdx.x * MTILE;

    // ---- H = silu(X @ W_in + b_in), plus one-time augmentation columns ----
#pragma unroll 4
    for (int j = 0; j < (MTILE * NN) / NTHREADS; ++j) {
        int idx = tid + j * NTHREADS;
        int r = idx >> 9;
        int c = idx & (NN - 1);
        const float* xr = X + (size_t)(rbase + r) * DIN;
        float v = b_in[c];
#pragma unroll
        for (int k = 0; k < DIN; ++k) v += xr[k] * W_in[k * NN + c];
        Hb[r * LDA + c] = f2bf(silu_(v));
    }
    if (tid < MTILE) {
        int r = tid;
        const float* xr = X + (size_t)(rbase + r) * DIN;
#pragma unroll
        for (int k = 0; k < DIN; ++k) {
            Hb[r * LDA + NN + k] = f2bf(xr[k]);
            Tb[r * LDA + NN + k] = 0;
        }
        Hb[r * LDA + NN + DIN] = f2bf(1.0f);
        Tb[r * LDA + NN + DIN] = f2bf(1.0f);
        for (int k = NN + DIN + 1; k < KAUG; ++k) {
            Hb[r * LDA + k] = 0;
            Tb[r * LDA + k] = 0;
        }
    }
    __syncthreads();

    uint32_t Fpack[16];   // sigmoid(F) for this wave's 32x64 tile, packed bf16 pairs

    for (int layer = 0; layer < NLAYERS; ++layer) {
        const short* wF  = wmats + (size_t)(layer * 4 + 0) * WELEMS;
        const short* wU  = wmats + (size_t)(layer * 4 + 1) * WELEMS;
        const short* wO1 = wmats + (size_t)(layer * 4 + 2) * WELEMS;
        const short* wO2 = wmats + (size_t)(layer * 4 + 3) * WELEMS;

        // ---- Phase A: T = sigmoid(pre_U)*tanh(pre_O1) -> Tb; F kept packed in regs ----
        uint32_t Tpack[16];
        {
            f32x4 aO[2][4];
            mm2(Hb + r0w * LDA, wO1, n0, l16, quad, aO);
#pragma unroll
            for (int mt = 0; mt < 2; ++mt)
#pragma unroll
                for (int nt = 0; nt < 4; ++nt)
#pragma unroll
                    for (int rp = 0; rp < 2; ++rp) {
                        uint32_t lo = (uint16_t)f2bf(tanh_(aO[mt][nt][2 * rp + 0]));
                        uint32_t hi = (uint16_t)f2bf(tanh_(aO[mt][nt][2 * rp + 1]));
                        Tpack[mt * 8 + nt * 2 + rp] = lo | (hi << 16);
                    }
        }
        {
            f32x4 aU[2][4];
            mm2(Hb + r0w * LDA, wU, n0, l16, quad, aU);
#pragma unroll
            for (int mt = 0; mt < 2; ++mt)
#pragma unroll
                for (int nt = 0; nt < 4; ++nt)
#pragma unroll
                    for (int rg = 0; rg < 4; ++rg) {
                        uint32_t tp = Tpack[mt * 8 + nt * 2 + (rg >> 1)];
                        float to = bf2f((short)(uint16_t)((rg & 1) ? (tp >> 16) : (tp & 0xffffu)));
                        int row = r0w + mt * 16 + quad * 4 + rg;
                        int col = n0 + nt * 16 + l16;
                        Tb[row * LDA + col] = f2bf(sig_(aU[mt][nt][rg]) * to);
                    }
        }
        {
            f32x4 aF[2][4];
            mm2(Hb + r0w * LDA, wF, n0, l16, quad, aF);
#pragma unroll
            for (int mt = 0; mt < 2; ++mt)
#pragma unroll
                for (int nt = 0; nt < 4; ++nt)
#pragma unroll
                    for (int rp = 0; rp < 2; ++rp) {
                        uint32_t lo = (uint16_t)f2bf(sig_(aF[mt][nt][2 * rp + 0]));
                        uint32_t hi = (uint16_t)f2bf(sig_(aF[mt][nt][2 * rp + 1]));
                        Fpack[mt * 8 + nt * 2 + rp] = lo | (hi << 16);
                    }
        }
        __syncthreads();   // Tb complete everywhere; Hb reads as A-operand done

        // ---- Phase B: O2 = silu(T @ Wo2 + bo2); H = F*H + O2 (own tile only) ----
        {
            f32x4 aO2[2][4];
            mm2(Tb + r0w * LDA, wO2, n0, l16, quad, aO2);
#pragma unroll
            for (int mt = 0; mt < 2; ++mt)
#pragma unroll
                for (int nt = 0; nt < 4; ++nt)
#pragma unroll
                    for (int rg = 0; rg < 4; ++rg) {
                        uint32_t fp = Fpack[mt * 8 + nt * 2 + (rg >> 1)];
                        float f = bf2f((short)(uint16_t)((rg & 1) ? (fp >> 16) : (fp & 0xffffu)));
                        int row = r0w + mt * 16 + quad * 4 + rg;
                        int col = n0 + nt * 16 + l16;
                        float hold = bf2f(Hb[row * LDA + col]);
                        float o2 = silu_(aO2[mt][nt][rg]);
                        Hb[row * LDA + col] = f2bf(f * hold + o2);
                    }
        }
        __syncthreads();   // Hb fully updated before next layer reads all of it
    }

    // ---- out = silu(H @ W_out + b_out) ----
    {
        const int r = tid >> 4, q = tid & 15;
        const int c0 = q * (NN / 16);
        float p = 0.0f;
        for (int c = c0; c < c0 + NN / 16; ++c)
            p += bf2f(Hb[r * LDA + c]) * W_out[c];
        float* red = (float*)Tb;     // Tb is free now
        red[tid] = p;
        __syncthreads();
        if (q == 0) {
            float s = b_out[0];
#pragma unroll
            for (int i = 0; i < 16; ++i) s += red[r * 16 + i];
            out[rbase + r] = silu_(s);
        }
    }
}

extern "C" void kernel_launch(void* const* d_in, const int* in_sizes, int n_in,
                              void* d_out, int out_size, void* d_ws, size_t ws_size,
                              hipStream_t stream) {
    const float* X     = (const float*)d_in[0];
    const float* W_in  = (const float*)d_in[1];
    const float* b_in  = (const float*)d_in[2];
    const float* Wf    = (const float*)d_in[3];
    const float* Uf    = (const float*)d_in[4];
    const float* bf    = (const float*)d_in[5];
    const float* Wu    = (const float*)d_in[6];
    const float* Uu    = (const float*)d_in[7];
    const float* bu    = (const float*)d_in[8];
    const float* Wo1   = (const float*)d_in[9];
    const float* Uo1   = (const float*)d_in[10];
    const float* bo1   = (const float*)d_in[11];
    const float* Wo2   = (const float*)d_in[12];
    const float* bo2   = (const float*)d_in[13];
    const float* W_out = (const float*)d_in[14];
    const float* b_out = (const float*)d_in[15];
    float* out = (float*)d_out;
    short* ws  = (short*)d_ws;       // needs 12*512*544*2 = 6.7 MB

    const int B = in_sizes[0] / DIN;

    prep_kernel<<<(12 * WELEMS + 255) / 256, 256, 0, stream>>>(
        Wf, Uf, bf, Wu, Uu, bu, Wo1, Uo1, bo1, Wo2, bo2, ws);

    hipFuncSetAttribute((const void*)dgm_kernel,
                        hipFuncAttributeMaxDynamicSharedMemorySize, LDS_BYTES);
    dgm_kernel<<<B / MTILE, NTHREADS, LDS_BYTES, stream>>>(X, W_in, b_in, W_out, b_out, ws, out);
}

// Round 3
// 1266.680 us; speedup vs baseline: 1.5816x; 1.5816x over previous
//
#include <hip/hip_runtime.h>
#include <cstdint>
#include <cstddef>

#define NLAYERS 3
#define NN      512
#define DIN     4
#define MTILE   64            // batch rows per workgroup
#define KAUG    544           // 512 (H/T) + 4 (X) + 1 (bias one) + 27 zero pad
#define LDA     552           // LDS row stride in bf16 elems
#define WELEMS  (NN * KAUG)   // one prepared weight matrix, bf16 elems
#define LDS_BYTES (2 * MTILE * LDA * 2)
#define NTHREADS 1024         // 16 waves: one 32-col block per wave -> 4 waves/SIMD

typedef __attribute__((ext_vector_type(8))) short short8;   // 8 x bf16 (4 VGPRs)
typedef __attribute__((ext_vector_type(4))) float f32x4;    // MFMA accumulator

__device__ __forceinline__ short f2bf(float f) {
    union { float f; uint32_t u; } v; v.f = f;
    uint32_t r = v.u + 0x7fffu + ((v.u >> 16) & 1u);   // RNE
    return (short)(r >> 16);
}
__device__ __forceinline__ float bf2f(short s) {
    union { uint32_t u; float f; } v; v.u = ((uint32_t)(uint16_t)s) << 16;
    return v.f;
}
__device__ __forceinline__ float sig_(float x)  { return 1.0f / (1.0f + __expf(-x)); }
__device__ __forceinline__ float tanh_(float x) { return 1.0f - 2.0f / (1.0f + __expf(2.0f * x)); }
__device__ __forceinline__ float silu_(float x) { return x / (1.0f + __expf(-x)); }

// ---------------- prep: 12 transposed + augmented bf16 weight matrices in ws ------------
// mat m = layer*4 + {0:F,1:U,2:O1,3:O2}; Bt[n][kk]:
//   kk<512 -> U[kk][n]; 512..515 -> W[kk-512][n] (0 for O2); 516 -> bias[n]; else 0.
__global__ void prep_kernel(const float* __restrict__ Wf,  const float* __restrict__ Uf,  const float* __restrict__ bf,
                            const float* __restrict__ Wu,  const float* __restrict__ Uu,  const float* __restrict__ bu,
                            const float* __restrict__ Wo1, const float* __restrict__ Uo1, const float* __restrict__ bo1,
                            const float* __restrict__ Wo2, const float* __restrict__ bo2,
                            short* __restrict__ ws) {
    int idx = blockIdx.x * 256 + threadIdx.x;
    int m   = idx / WELEMS;
    if (m >= 12) return;
    int rem = idx - m * WELEMS;
    int n   = rem / KAUG;
    int kk  = rem - n * KAUG;
    int layer = m >> 2, t = m & 3;
    const float* U; const float* W; const float* b;
    switch (t) {
        case 0:  U = Uf;  W = Wf;      b = bf;  break;
        case 1:  U = Uu;  W = Wu;      b = bu;  break;
        case 2:  U = Uo1; W = Wo1;     b = bo1; break;
        default: U = Wo2; W = nullptr; b = bo2; break;
    }
    float val = 0.0f;
    if (kk < NN)             val = U[layer * NN * NN + kk * NN + n];
    else if (kk < NN + DIN)  val = W ? W[layer * DIN * NN + (kk - NN) * NN + n] : 0.0f;
    else if (kk == NN + DIN) val = b[layer * NN + n];
    ws[idx] = f2bf(val);
}

// 64x32 @ K=544 MFMA block: A from LDS, Bt from global.
// A: distance-1 ping-pong (proven). B: 4-deep rolling prefetch (distance 4 K-halves)
// so each B fragment is issued ~620 interleaved pipe-cycles before its MFMA consumes
// it -> covers L2 (~200-400 cyc) latency regardless of wave stagger.
// 17 K-halves total: 3 x 4-half pipelined loop + 5-half static tail (no OOB loads).
__device__ __forceinline__ void mm1(const short* __restrict__ Asrc, const short* __restrict__ Bt,
                                    int n0, int l16, int quad, f32x4 (&acc)[4][2]) {
#pragma unroll
    for (int mt = 0; mt < 4; ++mt)
#pragma unroll
        for (int nt = 0; nt < 2; ++nt) acc[mt][nt] = f32x4{0.f, 0.f, 0.f, 0.f};
    const short* aP = Asrc + l16 * LDA + quad * 8;
    const short* bP = Bt + (size_t)(n0 + l16) * KAUG + quad * 8;

    short8 a0[4], a1[4];
    short8 b0[2], b1[2], b2[2], b3[2];

#pragma unroll
    for (int mt = 0; mt < 4; ++mt) a0[mt] = *(const short8*)(aP + mt * 16 * LDA);
#pragma unroll
    for (int nt = 0; nt < 2; ++nt) {
        b0[nt] = *(const short8*)(bP + nt * 16 * KAUG);
        b1[nt] = *(const short8*)(bP + nt * 16 * KAUG + 32);
        b2[nt] = *(const short8*)(bP + nt * 16 * KAUG + 64);
        b3[nt] = *(const short8*)(bP + nt * 16 * KAUG + 96);
    }

#pragma unroll 1
    for (int i = 0; i < 3; ++i) {          // halves 4i .. 4i+3  (0..11)
#pragma unroll
        for (int mt = 0; mt < 4; ++mt) a1[mt] = *(const short8*)(aP + mt * 16 * LDA + 32);
#pragma unroll
        for (int mt = 0; mt < 4; ++mt) {
            acc[mt][0] = __builtin_amdgcn_mfma_f32_16x16x32_bf16(a0[mt], b0[0], acc[mt][0], 0, 0, 0);
            acc[mt][1] = __builtin_amdgcn_mfma_f32_16x16x32_bf16(a0[mt], b0[1], acc[mt][1], 0, 0, 0);
        }
#pragma unroll
        for (int mt = 0; mt < 4; ++mt) a0[mt] = *(const short8*)(aP + mt * 16 * LDA + 64);
#pragma unroll
        for (int nt = 0; nt < 2; ++nt) b0[nt] = *(const short8*)(bP + nt * 16 * KAUG + 128); // B[4i+4]
#pragma unroll
        for (int mt = 0; mt < 4; ++mt) {
            acc[mt][0] = __builtin_amdgcn_mfma_f32_16x16x32_bf16(a1[mt], b1[0], acc[mt][0], 0, 0, 0);
            acc[mt][1] = __builtin_amdgcn_mfma_f32_16x16x32_bf16(a1[mt], b1[1], acc[mt][1], 0, 0, 0);
        }
#pragma unroll
        for (int mt = 0; mt < 4; ++mt) a1[mt] = *(const short8*)(aP + mt * 16 * LDA + 96);
#pragma unroll
        for (int nt = 0; nt < 2; ++nt) b1[nt] = *(const short8*)(bP + nt * 16 * KAUG + 160); // B[4i+5]
#pragma unroll
        for (int mt = 0; mt < 4; ++mt) {
            acc[mt][0] = __builtin_amdgcn_mfma_f32_16x16x32_bf16(a0[mt], b2[0], acc[mt][0], 0, 0, 0);
            acc[mt][1] = __builtin_amdgcn_mfma_f32_16x16x32_bf16(a0[mt], b2[1], acc[mt][1], 0, 0, 0);
        }
#pragma unroll
        for (int mt = 0; mt < 4; ++mt) a0[mt] = *(const short8*)(aP + mt * 16 * LDA + 128);
#pragma unroll
        for (int nt = 0; nt < 2; ++nt) b2[nt] = *(const short8*)(bP + nt * 16 * KAUG + 192); // B[4i+6]
#pragma unroll
        for (int mt = 0; mt < 4; ++mt) {
            acc[mt][0] = __builtin_amdgcn_mfma_f32_16x16x32_bf16(a1[mt], b3[0], acc[mt][0], 0, 0, 0);
            acc[mt][1] = __builtin_amdgcn_mfma_f32_16x16x32_bf16(a1[mt], b3[1], acc[mt][1], 0, 0, 0);
        }
#pragma unroll
        for (int nt = 0; nt < 2; ++nt) b3[nt] = *(const short8*)(bP + nt * 16 * KAUG + 224); // B[4i+7]
        aP += 128; bP += 128;
    }
    // tail: halves 12..16; here b0..b3 = B[12..15], a0 = A[12]
#pragma unroll
    for (int mt = 0; mt < 4; ++mt) a1[mt] = *(const short8*)(aP + mt * 16 * LDA + 32);      // A[13]
#pragma unroll
    for (int mt = 0; mt < 4; ++mt) {
        acc[mt][0] = __builtin_amdgcn_mfma_f32_16x16x32_bf16(a0[mt], b0[0], acc[mt][0], 0, 0, 0);  // h12
        acc[mt][1] = __builtin_amdgcn_mfma_f32_16x16x32_bf16(a0[mt], b0[1], acc[mt][1], 0, 0, 0);
    }
#pragma unroll
    for (int mt = 0; mt < 4; ++mt) a0[mt] = *(const short8*)(aP + mt * 16 * LDA + 64);      // A[14]
#pragma unroll
    for (int nt = 0; nt < 2; ++nt) b0[nt] = *(const short8*)(bP + nt * 16 * KAUG + 128);    // B[16]
#pragma unroll
    for (int mt = 0; mt < 4; ++mt) {
        acc[mt][0] = __builtin_amdgcn_mfma_f32_16x16x32_bf16(a1[mt], b1[0], acc[mt][0], 0, 0, 0);  // h13
        acc[mt][1] = __builtin_amdgcn_mfma_f32_16x16x32_bf16(a1[mt], b1[1], acc[mt][1], 0, 0, 0);
    }
#pragma unroll
    for (int mt = 0; mt < 4; ++mt) a1[mt] = *(const short8*)(aP + mt * 16 * LDA + 96);      // A[15]
#pragma unroll
    for (int mt = 0; mt < 4; ++mt) {
        acc[mt][0] = __builtin_amdgcn_mfma_f32_16x16x32_bf16(a0[mt], b2[0], acc[mt][0], 0, 0, 0);  // h14
        acc[mt][1] = __builtin_amdgcn_mfma_f32_16x16x32_bf16(a0[mt], b2[1], acc[mt][1], 0, 0, 0);
    }
#pragma unroll
    for (int mt = 0; mt < 4; ++mt) a0[mt] = *(const short8*)(aP + mt * 16 * LDA + 128);     // A[16]
#pragma unroll
    for (int mt = 0; mt < 4; ++mt) {
        acc[mt][0] = __builtin_amdgcn_mfma_f32_16x16x32_bf16(a1[mt], b3[0], acc[mt][0], 0, 0, 0);  // h15
        acc[mt][1] = __builtin_amdgcn_mfma_f32_16x16x32_bf16(a1[mt], b3[1], acc[mt][1], 0, 0, 0);
    }
#pragma unroll
    for (int mt = 0; mt < 4; ++mt) {
        acc[mt][0] = __builtin_amdgcn_mfma_f32_16x16x32_bf16(a0[mt], b0[0], acc[mt][0], 0, 0, 0);  // h16
        acc[mt][1] = __builtin_amdgcn_mfma_f32_16x16x32_bf16(a0[mt], b0[1], acc[mt][1], 0, 0, 0);
    }
}

// ---------------- fused DGM kernel: one 16-wave workgroup = 64 batch rows ----------------
__global__ void __launch_bounds__(NTHREADS, 4)
dgm_kernel(const float* __restrict__ X, const float* __restrict__ W_in, const float* __restrict__ b_in,
           const float* __restrict__ W_out, const float* __restrict__ b_out,
           const short* __restrict__ wmats, float* __restrict__ out) {
    extern __shared__ short lds[];
    short* Hb = lds;                 // [MTILE][LDA]  bf16, cols 512..516 = [X|1]
    short* Tb = lds + MTILE * LDA;   // [MTILE][LDA]  bf16, same augmentation (0,0,0,0,1)

    const int tid  = threadIdx.x;
    const int lane = tid & 63;
    const int wv   = tid >> 6;       // wave 0..15
    const int l16  = lane & 15;
    const int quad = lane >> 4;
    const int n0   = wv * 32;        // this wave's 32-column block
    const int rbase = blockIdx.x * MTILE;

    // ---- H = silu(X @ W_in + b_in), plus one-time augmentation columns ----
#pragma unroll 4
    for (int j = 0; j < (MTILE * NN) / NTHREADS; ++j) {
        int idx = tid + j * NTHREADS;
        int r = idx >> 9;
        int c = idx & (NN - 1);
        const float* xr = X + (size_t)(rbase + r) * DIN;
        float v = b_in[c];
#pragma unroll
        for (int k = 0; k < DIN; ++k) v += xr[k] * W_in[k * NN + c];
        Hb[r * LDA + c] = f2bf(silu_(v));
    }
    if (tid < MTILE) {
        int r = tid;
        const float* xr = X + (size_t)(rbase + r) * DIN;
#pragma unroll
        for (int k = 0; k < DIN; ++k) {
            Hb[r * LDA + NN + k] = f2bf(xr[k]);
            Tb[r * LDA + NN + k] = 0;
        }
        Hb[r * LDA + NN + DIN] = f2bf(1.0f);
        Tb[r * LDA + NN + DIN] = f2bf(1.0f);
        for (int k = NN + DIN + 1; k < KAUG; ++k) {
            Hb[r * LDA + k] = 0;
            Tb[r * LDA + k] = 0;
        }
    }
    __syncthreads();

    uint32_t Fpack[16];   // sigmoid(F) for this wave's 64x32 tile, packed bf16 pairs

    for (int layer = 0; layer < NLAYERS; ++layer) {
        const short* wF  = wmats + (size_t)(layer * 4 + 0) * WELEMS;
        const short* wU  = wmats + (size_t)(layer * 4 + 1) * WELEMS;
        const short* wO1 = wmats + (size_t)(layer * 4 + 2) * WELEMS;
        const short* wO2 = wmats + (size_t)(layer * 4 + 3) * WELEMS;

        // ---- Phase A: T = sigmoid(pre_U)*tanh(pre_O1) -> Tb; F kept packed in regs ----
        uint32_t Tpack[16];
        {
            f32x4 aO[4][2];
            mm1(Hb, wO1, n0, l16, quad, aO);
#pragma unroll
            for (int mt = 0; mt < 4; ++mt)
#pragma unroll
                for (int nt = 0; nt < 2; ++nt)
#pragma unroll
                    for (int rp = 0; rp < 2; ++rp) {
                        uint32_t lo = (uint16_t)f2bf(tanh_(aO[mt][nt][2 * rp + 0]));
                        uint32_t hi = (uint16_t)f2bf(tanh_(aO[mt][nt][2 * rp + 1]));
                        Tpack[mt * 4 + nt * 2 + rp] = lo | (hi << 16);
                    }
        }
        {
            f32x4 aU[4][2];
            mm1(Hb, wU, n0, l16, quad, aU);
#pragma unroll
            for (int mt = 0; mt < 4; ++mt)
#pragma unroll
                for (int nt = 0; nt < 2; ++nt)
#pragma unroll
                    for (int rg = 0; rg < 4; ++rg) {
                        uint32_t tp = Tpack[mt * 4 + nt * 2 + (rg >> 1)];
                        float to = bf2f((short)(uint16_t)((rg & 1) ? (tp >> 16) : (tp & 0xffffu)));
                        int row = mt * 16 + quad * 4 + rg;
                        int col = n0 + nt * 16 + l16;
                        Tb[row * LDA + col] = f2bf(sig_(aU[mt][nt][rg]) * to);
                    }
        }
        {
            f32x4 aF[4][2];
            mm1(Hb, wF, n0, l16, quad, aF);
#pragma unroll
            for (int mt = 0; mt < 4; ++mt)
#pragma unroll
                for (int nt = 0; nt < 2; ++nt)
#pragma unroll
                    for (int rp = 0; rp < 2; ++rp) {
                        uint32_t lo = (uint16_t)f2bf(sig_(aF[mt][nt][2 * rp + 0]));
                        uint32_t hi = (uint16_t)f2bf(sig_(aF[mt][nt][2 * rp + 1]));
                        Fpack[mt * 4 + nt * 2 + rp] = lo | (hi << 16);
                    }
        }
        __syncthreads();   // Tb complete everywhere; Hb reads as A-operand done

        // ---- Phase B: O2 = silu(T @ Wo2 + bo2); H = F*H + O2 (own tile only) ----
        {
            f32x4 aO2[4][2];
            mm1(Tb, wO2, n0, l16, quad, aO2);
#pragma unroll
            for (int mt = 0; mt < 4; ++mt)
#pragma unroll
                for (int nt = 0; nt < 2; ++nt)
#pragma unroll
                    for (int rg = 0; rg < 4; ++rg) {
                        uint32_t fp = Fpack[mt * 4 + nt * 2 + (rg >> 1)];
                        float f = bf2f((short)(uint16_t)((rg & 1) ? (fp >> 16) : (fp & 0xffffu)));
                        int row = mt * 16 + quad * 4 + rg;
                        int col = n0 + nt * 16 + l16;
                        float hold = bf2f(Hb[row * LDA + col]);
                        float o2 = silu_(aO2[mt][nt][rg]);
                        Hb[row * LDA + col] = f2bf(f * hold + o2);
                    }
        }
        __syncthreads();   // Hb fully updated before next layer reads all of it
    }

    // ---- out = silu(H @ W_out + b_out) ----
    {
        const int r = tid >> 4, q = tid & 15;
        const int c0 = q * (NN / 16);
        float p = 0.0f;
        for (int c = c0; c < c0 + NN / 16; ++c)
            p += bf2f(Hb[r * LDA + c]) * W_out[c];
        float* red = (float*)Tb;     // Tb is free now
        red[tid] = p;
        __syncthreads();
        if (q == 0) {
            float s = b_out[0];
#pragma unroll
            for (int i = 0; i < 16; ++i) s += red[r * 16 + i];
            out[rbase + r] = silu_(s);
        }
    }
}

extern "C" void kernel_launch(void* const* d_in, const int* in_sizes, int n_in,
                              void* d_out, int out_size, void* d_ws, size_t ws_size,
                              hipStream_t stream) {
    const float* X     = (const float*)d_in[0];
    const float* W_in  = (const float*)d_in[1];
    const float* b_in  = (const float*)d_in[2];
    const float* Wf    = (const float*)d_in[3];
    const float* Uf    = (const float*)d_in[4];
    const float* bf    = (const float*)d_in[5];
    const float* Wu    = (const float*)d_in[6];
    const float* Uu    = (const float*)d_in[7];
    const float* bu    = (const float*)d_in[8];
    const float* Wo1   = (const float*)d_in[9];
    const float* Uo1   = (const float*)d_in[10];
    const float* bo1   = (const float*)d_in[11];
    const float* Wo2   = (const float*)d_in[12];
    const float* bo2   = (const float*)d_in[13];
    const float* W_out = (const float*)d_in[14];
    const float* b_out = (const float*)d_in[15];
    float* out = (float*)d_out;
    short* ws  = (short*)d_ws;       // needs 12*512*544*2 = 6.7 MB

    const int B = in_sizes[0] / DIN;

    prep_kernel<<<(12 * WELEMS + 255) / 256, 256, 0, stream>>>(
        Wf, Uf, bf, Wu, Uu, bu, Wo1, Uo1, bo1, Wo2, bo2, ws);

    hipFuncSetAttribute((const void*)dgm_kernel,
                        hipFuncAttributeMaxDynamicSharedMemorySize, LDS_BYTES);
    dgm_kernel<<<B / MTILE, NTHREADS, LDS_BYTES, stream>>>(X, W_in, b_in, W_out, b_out, ws, out);
}